// Round 1
// baseline (2140.292 us; speedup 1.0000x reference)
//
#include <hip/hip_runtime.h>
#include <hip/hip_bf16.h>
#include <math.h>

// Problem constants (match reference)
#define N        1500
#define NE       1200
#define NPAD     1536          // padded neuron dim (i and k/j)
#define BATCH    96
#define NSTEP    60
#define KSPLIT   16
#define KCHUNK   (NPAD / KSPLIT)   // 96
#define PI_F     3.14159265358979323846f

// ---------------- phi (Ricciardi LIF transfer, Sanzeni approximation) -------

__device__ __forceinline__ float f_ricci(float x) {
    float z = x / (1.0f + x);
    float t = -z;
    // polyval coeffs a9..a1, 0 (highest degree first)
    float p = 0.14805913578876898f;
    p = p * t + 0.64290613877355551f;
    p = p * t + 1.0616084849547165f;
    p = p * t + 0.93524391761244940f;
    p = p * t + 0.62718906618071668f;
    p = p * t + 0.32171431660633076f;
    p = p * t + 0.32056016125642045f;
    p = p * t + 0.77373949685442023f;
    p = p * t + 0.22757881388024176f;
    p = p * t;                         // last coeff 0
    return logf(2.0f * x + 1.0f) + p;
}

__device__ __forceinline__ float g_ricci(float x) {
    float z = x / (2.0f + x);
    float num = z * (3.5441754117462949f + z * (-7.0529131065835378f + z * (-56.532378057580381f
        + z * (279.56761105465944f + z * (-520.37554849441472f + z * (456.58245777026514f
        + z * (-155.73340457809226f)))))));
    float den = 1.0f + z * (-4.1357968834226053f + z * (-7.2984226138266743f + z * (98.656602235468327f
        + z * (-334.20436223415163f + z * (601.08633903294185f + z * (-599.58577549598340f
        + z * (277.18420330693891f + z * (-16.445022798669722f))))))));
    return num / den;
}

__device__ __forceinline__ float phi_lif(float mu, float sig, float tau, float tau_ref) {
    float xp = mu / sig;                 // VR = 0
    float xm = (mu - 20.0f) / sig;       // VT = 20
    float r0;
    if (xm > 0.0f) {
        r0 = 1.0f / (f_ricci(xp) - f_ricci(xm));
    } else if (xp > 0.0f) {
        r0 = 1.0f / (f_ricci(xp) + expf(xm * xm) * g_ricci(-xm));
    } else {
        float a = g_ricci(-xm) - expf(xp * xp - xm * xm) * g_ricci(-xp);
        r0 = expf(-xm * xm - logf(a));
    }
    r0 = fmaxf(r0, 1e-30f);
    return 1.0f / (tau_ref + tau / r0);
}

// ---------------- preferred orientation -------------------------------------

__device__ __forceinline__ float pref_of(int n) {
    // linspace(0, 179.99, Ne/Ni, endpoint=False)
    const float stepE = 179.99f / 1200.0f;
    const float stepI = 179.99f / 300.0f;
    return (n < NE) ? (float)n * stepE : (float)(n - NE) * stepI;
}

// ---------------- kernel 1: build transposed fused weights ------------------
// WW[j*NPAD + i] = (W[i][j], W[i][j]^2);  j is the reduction (source) index.

__global__ __launch_bounds__(256) void k_weights(const float* __restrict__ hyp,
                                                 const float* __restrict__ rand_mat,
                                                 float2* __restrict__ WW) {
    int i = blockIdx.x * 256 + threadIdx.x;   // dest neuron (contiguous)
    int j = blockIdx.y;                        // src neuron
    if (i >= NPAD) return;
    if (i >= N || j >= N) {
        WW[(size_t)j * NPAD + i] = make_float2(0.0f, 0.0f);
        return;
    }
    float pi = pref_of(i), pj = pref_of(j);
    float diff = fabsf(pi - pj);
    int conn = (i >= NE ? 1 : 0) + 2 * (j >= NE ? 1 : 0);
    float J  = hyp[conn];
    float P  = hyp[4 + conn];
    float Wp = hyp[8 + conn];
    float denom = 4.0f * (PI_F / 180.0f * Wp) * (PI_F / 180.0f * Wp);
    float z = expf((cosf(2.0f * PI_F / 180.0f * diff) - 1.0f) / denom);
    float x = 32.0f * (P * z - rand_mat[(size_t)i * N + j]);
    float s = 1.0f / (1.0f + expf(-x));
    float w = J * s;
    WW[(size_t)j * NPAD + i] = make_float2(w, w * w);
}

// ---------------- kernel 2: mean + zero-init rate buffers -------------------

__global__ __launch_bounds__(256) void k_meaninit(float* __restrict__ mean,
                                                  float* __restrict__ rateA,
                                                  float* __restrict__ rateB) {
    int i = blockIdx.x * 256 + threadIdx.x;   // neuron
    int b = blockIdx.y;                        // batch = c*12 + o
    if (i >= NPAD) return;
    int c = b / 12, o = b % 12;
    const float contrasts[8] = {0.0f, 0.0432773f, 0.103411f, 0.186966f,
                                0.303066f, 0.464386f, 0.68854f, 1.0f};
    float m = 0.0f;
    if (i < N) {
        float orient = 15.0f * (float)o;
        float dth = orient - pref_of(i);
        const float denom = 4.0f * (PI_F / 180.0f * 30.0f) * (PI_F / 180.0f * 30.0f);
        float cg = expf((cosf(2.0f * PI_F / 180.0f * dth) - 1.0f) / denom);
        m = contrasts[c] * 20.0f * cg;
    }
    size_t idx = (size_t)b * NPAD + i;
    mean[idx]  = m;
    rateA[idx] = 0.0f;
    rateB[idx] = 0.0f;
}

// ---------------- kernel 3: GEMM partial (K-split) --------------------------
// part[(ks*BATCH + b)*NPAD + i] = (sum_k rate[b][k] W[i][k],  sum_k rate[b][k] W2[i][k])
// over k in [ks*KCHUNK, (ks+1)*KCHUNK)

__global__ __launch_bounds__(256) void k_gemm(const float2* __restrict__ WW,
                                              const float* __restrict__ rate,
                                              float2* __restrict__ part) {
    const int it = blockIdx.x;   // 0..5   (i tile of 256)
    const int bt = blockIdx.y;   // 0..5   (batch tile of 16)
    const int ks = blockIdx.z;   // 0..KSPLIT-1
    const int tid = threadIdx.x;
    const int i = it * 256 + tid;
    const int k0 = ks * KCHUNK;

    __shared__ float rl[16 * KCHUNK];   // 16 batches x KCHUNK  (6 KB)
    for (int t = tid; t < 16 * KCHUNK; t += 256) {
        int b = t / KCHUNK;
        int k = t - b * KCHUNK;
        rl[t] = rate[(size_t)(bt * 16 + b) * NPAD + k0 + k];
    }
    __syncthreads();

    float a1[16], a2[16];
#pragma unroll
    for (int b = 0; b < 16; b++) { a1[b] = 0.0f; a2[b] = 0.0f; }

    for (int kk = 0; kk < KCHUNK; kk += 4) {
        float2 w0 = WW[(size_t)(k0 + kk + 0) * NPAD + i];
        float2 w1 = WW[(size_t)(k0 + kk + 1) * NPAD + i];
        float2 w2 = WW[(size_t)(k0 + kk + 2) * NPAD + i];
        float2 w3 = WW[(size_t)(k0 + kk + 3) * NPAD + i];
#pragma unroll
        for (int b = 0; b < 16; b++) {
            float4 r = *(const float4*)&rl[b * KCHUNK + kk];
            a1[b] = fmaf(r.x, w0.x, a1[b]);  a2[b] = fmaf(r.x, w0.y, a2[b]);
            a1[b] = fmaf(r.y, w1.x, a1[b]);  a2[b] = fmaf(r.y, w1.y, a2[b]);
            a1[b] = fmaf(r.z, w2.x, a1[b]);  a2[b] = fmaf(r.z, w2.y, a2[b]);
            a1[b] = fmaf(r.w, w3.x, a1[b]);  a2[b] = fmaf(r.w, w3.y, a2[b]);
        }
    }

#pragma unroll
    for (int b = 0; b < 16; b++) {
        part[(size_t)(ks * BATCH + bt * 16 + b) * NPAD + i] = make_float2(a1[b], a2[b]);
    }
}

// ---------------- kernel 4: reduce partials + phi + Euler update ------------

__global__ __launch_bounds__(256) void k_update(const float2* __restrict__ part,
                                                const float* __restrict__ mean,
                                                const float* __restrict__ rate_in,
                                                float* __restrict__ rate_out) {
    int i = blockIdx.x * 256 + threadIdx.x;   // neuron (padded)
    int b = blockIdx.y;                        // batch
    if (i >= NPAD) return;
    size_t idx = (size_t)b * NPAD + i;

    float u1 = 0.0f, u2 = 0.0f;
#pragma unroll
    for (int ks = 0; ks < KSPLIT; ks++) {
        float2 p = part[(size_t)(ks * BATCH + b) * NPAD + i];
        u1 += p.x; u2 += p.y;
    }
    if (i >= N) { rate_out[idx] = 0.0f; return; }

    float mu  = 0.01f * u1 + mean[idx];
    float sig = sqrtf(0.01f * u2 + 25.0f);     // SIG_EXT^2 = 25
    float tau_ref = (i < NE) ? 0.005f : 0.001f;
    float Tinv    = (i < NE) ? 100.0f : 200.0f;
    float r = rate_in[idx];
    float ph = phi_lif(mu, sig, 0.01f, tau_ref);
    rate_out[idx] = r + 1e-3f * Tinv * (ph - r);
}

// ---------------- kernel 5: output transpose [b][i] -> [i][b] ---------------

__global__ __launch_bounds__(256) void k_out(const float* __restrict__ rate,
                                             float* __restrict__ out) {
    int idx = blockIdx.x * 256 + threadIdx.x;
    if (idx >= N * BATCH) return;
    int i = idx / BATCH;
    int b = idx - i * BATCH;
    out[idx] = rate[(size_t)b * NPAD + i];
}

// ---------------- launch ----------------------------------------------------

extern "C" void kernel_launch(void* const* d_in, const int* in_sizes, int n_in,
                              void* d_out, int out_size, void* d_ws, size_t ws_size,
                              hipStream_t stream) {
    const float* hyp      = (const float*)d_in[0];   // [3][4]
    const float* rand_mat = (const float*)d_in[1];   // [1500][1500]
    float* out            = (float*)d_out;           // [1500][8][12]

    // workspace layout (floats)
    float* ws = (float*)d_ws;
    float2* WW   = (float2*)ws;                                    // NPAD*NPAD float2
    float*  mean = ws + (size_t)NPAD * NPAD * 2;                   // BATCH*NPAD
    float*  rateA = mean  + (size_t)BATCH * NPAD;
    float*  rateB = rateA + (size_t)BATCH * NPAD;
    float2* part  = (float2*)(rateB + (size_t)BATCH * NPAD);       // KSPLIT*BATCH*NPAD float2

    k_weights<<<dim3(NPAD / 256, NPAD), 256, 0, stream>>>(hyp, rand_mat, WW);
    k_meaninit<<<dim3(NPAD / 256, BATCH), 256, 0, stream>>>(mean, rateA, rateB);

    float* buf[2] = {rateA, rateB};
    for (int s = 0; s < NSTEP; s++) {
        k_gemm<<<dim3(NPAD / 256, BATCH / 16, KSPLIT), 256, 0, stream>>>(WW, buf[s & 1], part);
        k_update<<<dim3(NPAD / 256, BATCH), 256, 0, stream>>>(part, mean, buf[s & 1], buf[(s + 1) & 1]);
    }
    // NSTEP even -> final rates in buf[0]
    k_out<<<(N * BATCH + 255) / 256, 256, 0, stream>>>(buf[0], out);
}

// Round 2
// 1397.078 us; speedup vs baseline: 1.5320x; 1.5320x over previous
//
#include <hip/hip_runtime.h>
#include <hip/hip_bf16.h>
#include <math.h>

// Problem constants (match reference)
#define N        1500
#define NE       1200
#define NPAD     1536          // padded neuron dim
#define BATCH    96
#define NSTEP    60
#define KSPLIT   16
#define KCHUNK   (NPAD / KSPLIT)   // 96 (3 MFMA K-steps of 32)
#define PI_F     3.14159265358979323846f

typedef __attribute__((ext_vector_type(8))) short short8b;  // 8 bf16 (4 VGPRs)
typedef __attribute__((ext_vector_type(4))) float f32x4;    // MFMA accumulator

// ---------------- bf16 split helpers ----------------------------------------

__device__ __forceinline__ ushort bf16_rn(float x) {
    unsigned u = __float_as_uint(x);
    unsigned r = (u + 0x7FFFu + ((u >> 16) & 1u)) >> 16;
    return (ushort)r;
}
__device__ __forceinline__ float bf16f(ushort h) {
    return __uint_as_float(((unsigned)h) << 16);
}

// ---------------- phi (Ricciardi LIF transfer, Sanzeni approximation) -------

__device__ __forceinline__ float f_ricci(float x) {
    float z = x / (1.0f + x);
    float t = -z;
    float p = 0.14805913578876898f;
    p = p * t + 0.64290613877355551f;
    p = p * t + 1.0616084849547165f;
    p = p * t + 0.93524391761244940f;
    p = p * t + 0.62718906618071668f;
    p = p * t + 0.32171431660633076f;
    p = p * t + 0.32056016125642045f;
    p = p * t + 0.77373949685442023f;
    p = p * t + 0.22757881388024176f;
    p = p * t;
    return logf(2.0f * x + 1.0f) + p;
}

__device__ __forceinline__ float g_ricci(float x) {
    float z = x / (2.0f + x);
    float num = z * (3.5441754117462949f + z * (-7.0529131065835378f + z * (-56.532378057580381f
        + z * (279.56761105465944f + z * (-520.37554849441472f + z * (456.58245777026514f
        + z * (-155.73340457809226f)))))));
    float den = 1.0f + z * (-4.1357968834226053f + z * (-7.2984226138266743f + z * (98.656602235468327f
        + z * (-334.20436223415163f + z * (601.08633903294185f + z * (-599.58577549598340f
        + z * (277.18420330693891f + z * (-16.445022798669722f))))))));
    return num / den;
}

__device__ __forceinline__ float phi_lif(float mu, float sig, float tau, float tau_ref) {
    float xp = mu / sig;                 // VR = 0
    float xm = (mu - 20.0f) / sig;       // VT = 20
    float r0;
    if (xm > 0.0f) {
        r0 = 1.0f / (f_ricci(xp) - f_ricci(xm));
    } else if (xp > 0.0f) {
        r0 = 1.0f / (f_ricci(xp) + expf(xm * xm) * g_ricci(-xm));
    } else {
        float a = g_ricci(-xm) - expf(xp * xp - xm * xm) * g_ricci(-xp);
        r0 = expf(-xm * xm - logf(a));
    }
    r0 = fmaxf(r0, 1e-30f);
    return 1.0f / (tau_ref + tau / r0);
}

__device__ __forceinline__ float pref_of(int n) {
    const float stepE = 179.99f / 1200.0f;
    const float stepI = 179.99f / 300.0f;
    return (n < NE) ? (float)n * stepE : (float)(n - NE) * stepI;
}

// ---------------- kernel 1: build bf16-split weight planes [i][k] -----------
// W[i][k]: dest i, source k.  4 planes: Whi, Wlo, W2hi, W2lo  (k contiguous)

__global__ __launch_bounds__(256) void k_weights(const float* __restrict__ hyp,
        const float* __restrict__ rand_mat,
        ushort* __restrict__ Whi, ushort* __restrict__ Wlo,
        ushort* __restrict__ W2hi, ushort* __restrict__ W2lo) {
    int k = blockIdx.x * 256 + threadIdx.x;   // source neuron j (contiguous)
    int i = blockIdx.y;                        // dest neuron
    size_t idx = (size_t)i * NPAD + k;
    if (i >= N || k >= N) {
        Whi[idx] = 0; Wlo[idx] = 0; W2hi[idx] = 0; W2lo[idx] = 0;
        return;
    }
    float pi = pref_of(i), pk = pref_of(k);
    float diff = fabsf(pi - pk);
    int conn = (i >= NE ? 1 : 0) + 2 * (k >= NE ? 1 : 0);
    float J  = hyp[conn];
    float P  = hyp[4 + conn];
    float Wp = hyp[8 + conn];
    float denom = 4.0f * (PI_F / 180.0f * Wp) * (PI_F / 180.0f * Wp);
    float z = expf((cosf(2.0f * PI_F / 180.0f * diff) - 1.0f) / denom);
    float x = 32.0f * (P * z - rand_mat[(size_t)i * N + k]);
    float s = 1.0f / (1.0f + expf(-x));
    float w = J * s;
    float w2 = w * w;
    ushort h = bf16_rn(w);
    Whi[idx] = h;  Wlo[idx] = bf16_rn(w - bf16f(h));
    ushort h2 = bf16_rn(w2);
    W2hi[idx] = h2; W2lo[idx] = bf16_rn(w2 - bf16f(h2));
}

// ---------------- kernel 2: mean + zero-init rate (fp32 + bf16 planes) ------

__global__ __launch_bounds__(256) void k_meaninit(float* __restrict__ mean,
                                                  float* __restrict__ rate,
                                                  ushort* __restrict__ rhi,
                                                  ushort* __restrict__ rlo) {
    int i = blockIdx.x * 256 + threadIdx.x;
    int b = blockIdx.y;                        // batch = c*12 + o
    int c = b / 12, o = b % 12;
    const float contrasts[8] = {0.0f, 0.0432773f, 0.103411f, 0.186966f,
                                0.303066f, 0.464386f, 0.68854f, 1.0f};
    float m = 0.0f;
    if (i < N) {
        float orient = 15.0f * (float)o;
        float dth = orient - pref_of(i);
        const float denom = 4.0f * (PI_F / 180.0f * 30.0f) * (PI_F / 180.0f * 30.0f);
        float cg = expf((cosf(2.0f * PI_F / 180.0f * dth) - 1.0f) / denom);
        m = contrasts[c] * 20.0f * cg;
    }
    size_t idx = (size_t)b * NPAD + i;
    mean[idx] = m;
    rate[idx] = 0.0f;
    rhi[idx]  = 0;
    rlo[idx]  = 0;
}

// ---------------- kernel 3: MFMA GEMM partial (K-split) ---------------------
// Wave covers [M=96 batches x N=16 i]; WG (4 waves) covers 64 i.
// part1/part2[(ks*96+b)*NPAD + i] = sum over k-chunk of rate*W / rate*W2.
// bf16 4-pass split: (ah+al)x(bh+bl), fp32 accumulate == fp32-grade precision.

__global__ __launch_bounds__(256) void k_gemm(
        const ushort* __restrict__ Whi, const ushort* __restrict__ Wlo,
        const ushort* __restrict__ W2hi, const ushort* __restrict__ W2lo,
        const ushort* __restrict__ rhi, const ushort* __restrict__ rlo,
        float* __restrict__ part1, float* __restrict__ part2) {
    const int tid  = threadIdx.x;
    const int wave = tid >> 6;
    const int lane = tid & 63;
    const int lr   = lane & 15;     // row-in-16 (A) / col (B, C)
    const int lq   = lane >> 4;     // k-quad
    const int i0   = blockIdx.x * 64 + wave * 16;      // wave's i tile
    const int k0   = blockIdx.y * KCHUNK;

    const size_t boff = (size_t)(i0 + lr) * NPAD + k0 + 8 * lq;

    f32x4 acc1[6], acc2[6];
#pragma unroll
    for (int m = 0; m < 6; m++) {
        acc1[m] = (f32x4){0.0f, 0.0f, 0.0f, 0.0f};
        acc2[m] = (f32x4){0.0f, 0.0f, 0.0f, 0.0f};
    }

#pragma unroll
    for (int kk = 0; kk < KCHUNK / 32; kk++) {
        const int kof = kk * 32;
        short8b bh  = *(const short8b*)(Whi  + boff + kof);
        short8b bl  = *(const short8b*)(Wlo  + boff + kof);
        short8b b2h = *(const short8b*)(W2hi + boff + kof);
        short8b b2l = *(const short8b*)(W2lo + boff + kof);
#pragma unroll
        for (int m = 0; m < 6; m++) {
            const size_t aoff = (size_t)(16 * m + lr) * NPAD + k0 + 8 * lq + kof;
            short8b ah = *(const short8b*)(rhi + aoff);
            short8b al = *(const short8b*)(rlo + aoff);
            acc1[m] = __builtin_amdgcn_mfma_f32_16x16x32_bf16(ah, bh,  acc1[m], 0, 0, 0);
            acc1[m] = __builtin_amdgcn_mfma_f32_16x16x32_bf16(ah, bl,  acc1[m], 0, 0, 0);
            acc1[m] = __builtin_amdgcn_mfma_f32_16x16x32_bf16(al, bh,  acc1[m], 0, 0, 0);
            acc1[m] = __builtin_amdgcn_mfma_f32_16x16x32_bf16(al, bl,  acc1[m], 0, 0, 0);
            acc2[m] = __builtin_amdgcn_mfma_f32_16x16x32_bf16(ah, b2h, acc2[m], 0, 0, 0);
            acc2[m] = __builtin_amdgcn_mfma_f32_16x16x32_bf16(ah, b2l, acc2[m], 0, 0, 0);
            acc2[m] = __builtin_amdgcn_mfma_f32_16x16x32_bf16(al, b2h, acc2[m], 0, 0, 0);
            acc2[m] = __builtin_amdgcn_mfma_f32_16x16x32_bf16(al, b2l, acc2[m], 0, 0, 0);
        }
    }

    // C/D layout: col = lane&15, row = (lane>>4)*4 + r
    const int ic = blockIdx.x * 64 + wave * 16 + lr;
#pragma unroll
    for (int m = 0; m < 6; m++) {
#pragma unroll
        for (int r = 0; r < 4; r++) {
            int b = 16 * m + 4 * lq + r;
            size_t o = (size_t)(blockIdx.y * BATCH + b) * NPAD + ic;
            part1[o] = acc1[m][r];
            part2[o] = acc2[m][r];
        }
    }
}

// ---------------- kernel 4: reduce partials + phi + Euler update (in-place) -

__global__ __launch_bounds__(256) void k_update(
        const float* __restrict__ part1, const float* __restrict__ part2,
        const float* __restrict__ mean, float* __restrict__ rate,
        ushort* __restrict__ rhi, ushort* __restrict__ rlo) {
    int i = blockIdx.x * 256 + threadIdx.x;
    int b = blockIdx.y;
    size_t idx = (size_t)b * NPAD + i;

    float u1 = 0.0f, u2 = 0.0f;
#pragma unroll
    for (int ks = 0; ks < KSPLIT; ks++) {
        size_t o = (size_t)(ks * BATCH + b) * NPAD + i;
        u1 += part1[o];
        u2 += part2[o];
    }
    if (i >= N) { rate[idx] = 0.0f; rhi[idx] = 0; rlo[idx] = 0; return; }

    float mu  = 0.01f * u1 + mean[idx];
    float sig = sqrtf(0.01f * u2 + 25.0f);     // SIG_EXT^2 = 25
    float tau_ref = (i < NE) ? 0.005f : 0.001f;
    float Tinv    = (i < NE) ? 100.0f : 200.0f;
    float r = rate[idx];
    float ph = phi_lif(mu, sig, 0.01f, tau_ref);
    float rn = r + 1e-3f * Tinv * (ph - r);
    rate[idx] = rn;
    ushort h = bf16_rn(rn);
    rhi[idx] = h;
    rlo[idx] = bf16_rn(rn - bf16f(h));
}

// ---------------- kernel 5: output transpose [b][i] -> [i][b] ---------------

__global__ __launch_bounds__(256) void k_out(const float* __restrict__ rate,
                                             float* __restrict__ out) {
    int idx = blockIdx.x * 256 + threadIdx.x;
    if (idx >= N * BATCH) return;
    int i = idx / BATCH;
    int b = idx - i * BATCH;
    out[idx] = rate[(size_t)b * NPAD + i];
}

// ---------------- launch ----------------------------------------------------

extern "C" void kernel_launch(void* const* d_in, const int* in_sizes, int n_in,
                              void* d_out, int out_size, void* d_ws, size_t ws_size,
                              hipStream_t stream) {
    const float* hyp      = (const float*)d_in[0];   // [3][4]
    const float* rand_mat = (const float*)d_in[1];   // [1500][1500]
    float* out            = (float*)d_out;           // [1500][8][12]

    char* p = (char*)d_ws;
    ushort* Whi  = (ushort*)p; p += (size_t)NPAD * NPAD * 2;
    ushort* Wlo  = (ushort*)p; p += (size_t)NPAD * NPAD * 2;
    ushort* W2hi = (ushort*)p; p += (size_t)NPAD * NPAD * 2;
    ushort* W2lo = (ushort*)p; p += (size_t)NPAD * NPAD * 2;
    float*  part1 = (float*)p; p += (size_t)KSPLIT * BATCH * NPAD * 4;
    float*  part2 = (float*)p; p += (size_t)KSPLIT * BATCH * NPAD * 4;
    float*  mean  = (float*)p; p += (size_t)BATCH * NPAD * 4;
    float*  rate  = (float*)p; p += (size_t)BATCH * NPAD * 4;
    ushort* rhi   = (ushort*)p; p += (size_t)BATCH * NPAD * 2;
    ushort* rlo   = (ushort*)p; p += (size_t)BATCH * NPAD * 2;

    k_weights<<<dim3(NPAD / 256, NPAD), 256, 0, stream>>>(hyp, rand_mat, Whi, Wlo, W2hi, W2lo);
    k_meaninit<<<dim3(NPAD / 256, BATCH), 256, 0, stream>>>(mean, rate, rhi, rlo);

    for (int s = 0; s < NSTEP; s++) {
        k_gemm<<<dim3(NPAD / 64, KSPLIT), 256, 0, stream>>>(Whi, Wlo, W2hi, W2lo,
                                                            rhi, rlo, part1, part2);
        k_update<<<dim3(NPAD / 256, BATCH), 256, 0, stream>>>(part1, part2, mean,
                                                              rate, rhi, rlo);
    }
    k_out<<<(N * BATCH + 255) / 256, 256, 0, stream>>>(rate, out);
}